// Round 9
// baseline (705.565 us; speedup 1.0000x reference)
//
#include <hip/hip_runtime.h>
#include <hip/hip_bf16.h>

// ISTA split-bf16 MFMA, round 9: two independent 16-row groups per block.
// C' = S · d^T (A = S register-resident, B = d from LDS, m89 C-layout).
// ROWS=32, grid=128, 8 waves: waves 0-3 -> group A (rows 0-15),
// waves 4-7 -> group B (rows 16-31). Each SIMD gets one A-wave + one
// B-wave; the groups are fully independent, so their dep-chain stalls
// interleave (real latency hiding, m114) with ZERO duplicated MFMAs
// (unlike R6: both groups are full 16-row tiles; per-CU MFMA=192/iter for
// 32 rows == 2x R7's 96 for 16 rows; chip-total identical on 128 CUs).
// R8 lesson: same-block barrier-locked waves don't hide each other's
// latency; R8's split-K second barrier round cost more than 2-wave TLP
// bought. Here: ONE barrier/iter, no exchange.
// Inner loop is R7's VALU-lean version verbatim (separate dh/dl u16 ->
// fragment-direct b128 reads; med3 softthr; cvt_pk_bf16; b64 writes).
// Per-output arithmetic identical to R7 -> absmax 0.03125 expected.

#define ROWS     32          // 2 groups x 16 rows
#define KPAD     128
#define N_DIM    100
#define M_DIM    70
#define NTHREADS 512

typedef __attribute__((ext_vector_type(8))) short short8;
typedef __attribute__((ext_vector_type(4))) float f32x4;

static __device__ __forceinline__ unsigned short f2bf(float f) {
    unsigned u = __float_as_uint(f);
    u += 0x7FFF + ((u >> 16) & 1);          // RNE
    return (unsigned short)(u >> 16);
}
static __device__ __forceinline__ float bf2f(unsigned short b) {
    return __uint_as_float(((unsigned)b) << 16);
}
// packed RNE: low16 = bf16(a), high16 = bf16(b)
static __device__ __forceinline__ unsigned cvt_pk_bf16(float a, float b) {
    unsigned r;
    asm("v_cvt_pk_bf16_f32 %0, %1, %2" : "=v"(r) : "v"(a), "v"(b));
    return r;
}
static __device__ __forceinline__ float med3f(float x, float lo, float hi) {
    float r;
    asm("v_med3_f32 %0, %1, %2, %3" : "=v"(r) : "v"(x), "v"(lo), "v"(hi));
    return r;
}

__global__ __launch_bounds__(NTHREADS, 2)
void ista_mfma7(const float* __restrict__ y,
                const float* __restrict__ S,
                const float* __restrict__ W,
                const float* __restrict__ thr,
                const int*   __restrict__ numIter,
                float* __restrict__ out)
{
    __shared__ __align__(16) unsigned short dh[2][ROWS * KPAD];  // d hi bf16 bits
    __shared__ __align__(16) unsigned short dl[2][ROWS * KPAD];  // d lo bf16 bits

    const int t    = threadIdx.x;
    const int wv   = t >> 6;        // wave 0..7
    const int l    = t & 63;
    const int l15  = l & 15;
    const int lg   = l >> 4;
    const int gid  = wv >> 2;       // group 0 (rows 0-15) / 1 (rows 16-31)
    const int gw   = wv & 3;        // wave within group: tiles 2gw, 2gw+1
    const int rowB = blockIdx.x * ROWS;          // block's first global row
    const int row0 = rowB + gid * 16;            // group's first global row
    const float th  = thr[0];
    const float nth = -th;
    const int iters = numIter[0];
    const unsigned swz = (unsigned)((l15 & 7) << 4);   // row&7 == l15&7 (gid*16 even)

    // ---- one-time: S fragments, A operand (row = l15 = j-in-tile) ----
    short8 Sh[2][4], Sl[2][4];
    #pragma unroll
    for (int n2 = 0; n2 < 2; ++n2) {
        const int jg = (gw * 2 + n2) * 16 + l15;           // global output column
        #pragma unroll
        for (int kt = 0; kt < 4; ++kt) {
            #pragma unroll
            for (int i = 0; i < 8; ++i) {
                const int k = kt * 32 + lg * 8 + i;
                const float v = (jg < N_DIM && k < N_DIM) ? S[jg * N_DIM + k] : 0.f;
                const unsigned short hb = f2bf(v);
                Sh[n2][kt][i] = (short)hb;
                Sl[n2][kt][i] = (short)f2bf(v - bf2f(hb));
            }
        }
    }

    // ---- one-time: Wy in C' layout (lane: d-row = row0+l15, j per tile) ----
    f32x4 Wyr[2];
    #pragma unroll
    for (int n2 = 0; n2 < 2; ++n2) {
        #pragma unroll
        for (int q = 0; q < 4; ++q) {
            const int j = (gw * 2 + n2) * 16 + lg * 4 + q;
            float acc = 0.f;
            if (j < N_DIM) {
                const float* yr = y + (size_t)(row0 + l15) * M_DIM;
                const float* wr = W + (size_t)j * M_DIM;
                #pragma unroll 10
                for (int m = 0; m < M_DIM; ++m) acc = fmaf(yr[m], wr[m], acc);
            }
            Wyr[n2][q] = acc;
        }
    }

    // ---- zero buffer 0 (both groups) ----
    for (int idx = t; idx < ROWS * KPAD; idx += NTHREADS) {
        dh[0][idx] = 0; dl[0][idx] = 0;
    }
    __syncthreads();

    // loop-invariant byte offsets; lane's LDS row = gid*16 + l15 (256B/row)
    const unsigned rowByte = (unsigned)((gid * 16 + l15) * 256);
    unsigned roff[4];
    #pragma unroll
    for (int kt = 0; kt < 4; ++kt)
        roff[kt] = (rowByte + (unsigned)(kt * 64 + lg * 16)) ^ swz;
    unsigned woff[2];
    #pragma unroll
    for (int n2 = 0; n2 < 2; ++n2)
        woff[n2] = (rowByte + (unsigned)((gw * 2 + n2) * 32 + lg * 8)) ^ swz;

    int cur = 0;
    for (int it = 0; it < iters; ++it) {
        const char* rh = (const char*)dh[cur];
        const char* rl = (const char*)dl[cur];
        char* wh = (char*)dh[cur ^ 1];
        char* wl = (char*)dl[cur ^ 1];

        // ---- 8 b128 reads: this group's d, fragments directly ----
        short8 Bh[4], Bl[4];
        #pragma unroll
        for (int kt = 0; kt < 4; ++kt) {
            Bh[kt] = *(const short8*)(rh + roff[kt]);
            Bl[kt] = *(const short8*)(rl + roff[kt]);
        }

        // ---- 24 MFMAs, 3 independent chains per N-tile (dep depth = 4) ----
        f32x4 Chh[2] = { Wyr[0], Wyr[1] };
        f32x4 Chl[2] = { {0,0,0,0}, {0,0,0,0} };
        f32x4 Clh[2] = { {0,0,0,0}, {0,0,0,0} };
        #pragma unroll
        for (int kt = 0; kt < 4; ++kt) {
            #pragma unroll
            for (int n2 = 0; n2 < 2; ++n2)
                Chh[n2] = __builtin_amdgcn_mfma_f32_16x16x32_bf16(Sh[n2][kt], Bh[kt], Chh[n2], 0, 0, 0);
            #pragma unroll
            for (int n2 = 0; n2 < 2; ++n2)
                Chl[n2] = __builtin_amdgcn_mfma_f32_16x16x32_bf16(Sh[n2][kt], Bl[kt], Chl[n2], 0, 0, 0);
            #pragma unroll
            for (int n2 = 0; n2 < 2; ++n2)
                Clh[n2] = __builtin_amdgcn_mfma_f32_16x16x32_bf16(Sl[n2][kt], Bh[kt], Clh[n2], 0, 0, 0);
        }

        // ---- epilogue: sum chains, med3-softthr, cvt_pk split, b64 writes ----
        #pragma unroll
        for (int n2 = 0; n2 < 2; ++n2) {
            float r0, r1, r2, r3;
            {
                const float s0 = Chh[n2][0] + Chl[n2][0] + Clh[n2][0];
                const float s1 = Chh[n2][1] + Chl[n2][1] + Clh[n2][1];
                const float s2 = Chh[n2][2] + Chl[n2][2] + Clh[n2][2];
                const float s3 = Chh[n2][3] + Chl[n2][3] + Clh[n2][3];
                r0 = s0 - med3f(s0, nth, th);
                r1 = s1 - med3f(s1, nth, th);
                r2 = s2 - med3f(s2, nth, th);
                r3 = s3 - med3f(s3, nth, th);
            }
            const unsigned h01 = cvt_pk_bf16(r0, r1);
            const unsigned h23 = cvt_pk_bf16(r2, r3);
            const float l0 = r0 - __uint_as_float(h01 << 16);
            const float l1 = r1 - __uint_as_float(h01 & 0xFFFF0000u);
            const float l2 = r2 - __uint_as_float(h23 << 16);
            const float l3 = r3 - __uint_as_float(h23 & 0xFFFF0000u);
            const unsigned lo01 = cvt_pk_bf16(l0, l1);
            const unsigned lo23 = cvt_pk_bf16(l2, l3);
            *(uint2*)(wh + woff[n2]) = make_uint2(h01, h23);
            *(uint2*)(wl + woff[n2]) = make_uint2(lo01, lo23);
        }

        __syncthreads();          // one barrier: publishes both groups' d
        cur ^= 1;
    }

    // ---- output: hi+lo recombine, write global (all 32 rows) ----
    for (int idx = t; idx < ROWS * N_DIM; idx += NTHREADS) {
        const int r = idx / N_DIM;
        const int j = idx - r * N_DIM;
        const unsigned off = ((unsigned)(r * 256 + j * 2)) ^ ((unsigned)((r & 7) << 4));
        const float v = bf2f(*(const unsigned short*)((const char*)dh[cur] + off))
                      + bf2f(*(const unsigned short*)((const char*)dl[cur] + off));
        out[(size_t)(rowB + r) * N_DIM + j] = v;
    }
}

extern "C" void kernel_launch(void* const* d_in, const int* in_sizes, int n_in,
                              void* d_out, int out_size, void* d_ws, size_t ws_size,
                              hipStream_t stream) {
    const float* y       = (const float*)d_in[0];
    const float* S       = (const float*)d_in[1];
    const float* W       = (const float*)d_in[2];
    const float* thr     = (const float*)d_in[3];
    const int*   numIter = (const int*)d_in[4];
    float* out = (float*)d_out;

    const int Brows = in_sizes[0] / M_DIM;   // 4096
    const int nblk  = Brows / ROWS;          // 128 blocks, 8 waves each
    ista_mfma7<<<nblk, NTHREADS, 0, stream>>>(y, S, W, thr, numIter, out);
}

// Round 11
// 464.381 us; speedup vs baseline: 1.5194x; 1.5194x over previous
//
#include <hip/hip_runtime.h>
#include <hip/hip_bf16.h>

// ISTA split-bf16 MFMA, round 10 (resubmit — R10 bench was an infra timeout):
// 8-wave COLUMN-split, 1 barrier, full chip.
// C' = S · d^T (A = S register-resident, B = d from LDS, m89 C-layout).
// ROWS=16, grid=256 (1 block/CU, all CUs), 8 waves = 2/SIMD; wave w owns
// N-tile w (cols 16w..16w+15; 8 tiles == R7's padding to 128).
// Rationale: R9 proved 2 independent waves/SIMD cut cy/MFMA 13.2 -> 8.7 but
// idled half the chip (rows can't fill it: 4096/16 = 256 groups). Column
// split keeps all 256 CUs busy, same 96 MFMAs/CU-iter, no duplicated work,
// no R8 exchange round: each wave reads full d (8 b128 -- every output col
// needs all K), 12 MFMAs (3 chains x 4 kt), half-size epilogue, b64x2
// writes in own column range, ONE barrier.
// Cost: LDS reads double (64 KB/iter/CU ~ 770 cy b128-throughput) -- the
// predicted new wall, overlapped across 2 waves/SIMD.
// Per-output arithmetic identical to R7 -> absmax 0.03125.

#define ROWS     16
#define KPAD     128
#define N_DIM    100
#define M_DIM    70
#define NTHREADS 512

typedef __attribute__((ext_vector_type(8))) short short8;
typedef __attribute__((ext_vector_type(4))) float f32x4;

static __device__ __forceinline__ unsigned short f2bf(float f) {
    unsigned u = __float_as_uint(f);
    u += 0x7FFF + ((u >> 16) & 1);          // RNE
    return (unsigned short)(u >> 16);
}
static __device__ __forceinline__ float bf2f(unsigned short b) {
    return __uint_as_float(((unsigned)b) << 16);
}
// packed RNE: low16 = bf16(a), high16 = bf16(b)
static __device__ __forceinline__ unsigned cvt_pk_bf16(float a, float b) {
    unsigned r;
    asm("v_cvt_pk_bf16_f32 %0, %1, %2" : "=v"(r) : "v"(a), "v"(b));
    return r;
}
static __device__ __forceinline__ float med3f(float x, float lo, float hi) {
    float r;
    asm("v_med3_f32 %0, %1, %2, %3" : "=v"(r) : "v"(x), "v"(lo), "v"(hi));
    return r;
}

__global__ __launch_bounds__(NTHREADS, 2)
void ista_mfma8(const float* __restrict__ y,
                const float* __restrict__ S,
                const float* __restrict__ W,
                const float* __restrict__ thr,
                const int*   __restrict__ numIter,
                float* __restrict__ out)
{
    __shared__ __align__(16) unsigned short dh[2][ROWS * KPAD];  // d hi bf16 bits
    __shared__ __align__(16) unsigned short dl[2][ROWS * KPAD];  // d lo bf16 bits

    const int t    = threadIdx.x;
    const int wv   = t >> 6;        // wave 0..7 = N-tile index
    const int l    = t & 63;
    const int l15  = l & 15;
    const int lg   = l >> 4;
    const int row0 = blockIdx.x * ROWS;
    const float th  = thr[0];
    const float nth = -th;
    const int iters = numIter[0];
    const unsigned swz = (unsigned)((l15 & 7) << 4);

    // ---- one-time: S fragments, A operand (row = l15 = j-in-tile) ----
    short8 Sh[4], Sl[4];
    {
        const int jg = wv * 16 + l15;                      // global output column
        #pragma unroll
        for (int kt = 0; kt < 4; ++kt) {
            #pragma unroll
            for (int i = 0; i < 8; ++i) {
                const int k = kt * 32 + lg * 8 + i;
                const float v = (jg < N_DIM && k < N_DIM) ? S[jg * N_DIM + k] : 0.f;
                const unsigned short hb = f2bf(v);
                Sh[kt][i] = (short)hb;
                Sl[kt][i] = (short)f2bf(v - bf2f(hb));
            }
        }
    }

    // ---- one-time: Wy in C' layout (lane: d-row = l15, j = wv*16 + lg*4+q) ----
    f32x4 Wyr;
    #pragma unroll
    for (int q = 0; q < 4; ++q) {
        const int j = wv * 16 + lg * 4 + q;
        float acc = 0.f;
        if (j < N_DIM) {
            const float* yr = y + (size_t)(row0 + l15) * M_DIM;
            const float* wr = W + (size_t)j * M_DIM;
            #pragma unroll 10
            for (int m = 0; m < M_DIM; ++m) acc = fmaf(yr[m], wr[m], acc);
        }
        Wyr[q] = acc;
    }

    // ---- zero buffer 0 ----
    for (int idx = t; idx < ROWS * KPAD; idx += NTHREADS) {
        dh[0][idx] = 0; dl[0][idx] = 0;
    }
    __syncthreads();

    // loop-invariant byte offsets (XOR swizzle on byte bits 4..6)
    unsigned roff[4];
    #pragma unroll
    for (int kt = 0; kt < 4; ++kt)
        roff[kt] = ((unsigned)(l15 * 256 + kt * 64 + lg * 16)) ^ swz;
    const unsigned woff = ((unsigned)(l15 * 256 + wv * 32 + lg * 8)) ^ swz;

    int cur = 0;
    for (int it = 0; it < iters; ++it) {
        const char* rh = (const char*)dh[cur];
        const char* rl = (const char*)dl[cur];
        char* wh = (char*)dh[cur ^ 1];
        char* wl = (char*)dl[cur ^ 1];

        // ---- 8 b128 reads: full d, fragments directly ----
        short8 Bh[4], Bl[4];
        #pragma unroll
        for (int kt = 0; kt < 4; ++kt) {
            Bh[kt] = *(const short8*)(rh + roff[kt]);
            Bl[kt] = *(const short8*)(rl + roff[kt]);
        }

        // ---- 12 MFMAs, 3 independent chains (dep depth = 4) ----
        f32x4 Chh = Wyr;
        f32x4 Chl = {0,0,0,0};
        f32x4 Clh = {0,0,0,0};
        #pragma unroll
        for (int kt = 0; kt < 4; ++kt) {
            Chh = __builtin_amdgcn_mfma_f32_16x16x32_bf16(Sh[kt], Bh[kt], Chh, 0, 0, 0);
            Chl = __builtin_amdgcn_mfma_f32_16x16x32_bf16(Sh[kt], Bl[kt], Chl, 0, 0, 0);
            Clh = __builtin_amdgcn_mfma_f32_16x16x32_bf16(Sl[kt], Bh[kt], Clh, 0, 0, 0);
        }

        // ---- epilogue: sum chains, med3-softthr, cvt_pk split, b64 writes ----
        float r0, r1, r2, r3;
        {
            const float s0 = Chh[0] + Chl[0] + Clh[0];
            const float s1 = Chh[1] + Chl[1] + Clh[1];
            const float s2 = Chh[2] + Chl[2] + Clh[2];
            const float s3 = Chh[3] + Chl[3] + Clh[3];
            r0 = s0 - med3f(s0, nth, th);
            r1 = s1 - med3f(s1, nth, th);
            r2 = s2 - med3f(s2, nth, th);
            r3 = s3 - med3f(s3, nth, th);
        }
        const unsigned h01 = cvt_pk_bf16(r0, r1);
        const unsigned h23 = cvt_pk_bf16(r2, r3);
        const float l0 = r0 - __uint_as_float(h01 << 16);
        const float l1 = r1 - __uint_as_float(h01 & 0xFFFF0000u);
        const float l2 = r2 - __uint_as_float(h23 << 16);
        const float l3 = r3 - __uint_as_float(h23 & 0xFFFF0000u);
        const unsigned lo01 = cvt_pk_bf16(l0, l1);
        const unsigned lo23 = cvt_pk_bf16(l2, l3);
        *(uint2*)(wh + woff) = make_uint2(h01, h23);
        *(uint2*)(wl + woff) = make_uint2(lo01, lo23);

        __syncthreads();          // one barrier: all 8 waves published their cols
        cur ^= 1;
    }

    // ---- output: hi+lo recombine, write global ----
    for (int idx = t; idx < ROWS * N_DIM; idx += NTHREADS) {
        const int r = idx / N_DIM;
        const int j = idx - r * N_DIM;
        const unsigned off = ((unsigned)(r * 256 + j * 2)) ^ ((unsigned)((r & 7) << 4));
        const float v = bf2f(*(const unsigned short*)((const char*)dh[cur] + off))
                      + bf2f(*(const unsigned short*)((const char*)dl[cur] + off));
        out[(size_t)(row0 + r) * N_DIM + j] = v;
    }
}

extern "C" void kernel_launch(void* const* d_in, const int* in_sizes, int n_in,
                              void* d_out, int out_size, void* d_ws, size_t ws_size,
                              hipStream_t stream) {
    const float* y       = (const float*)d_in[0];
    const float* S       = (const float*)d_in[1];
    const float* W       = (const float*)d_in[2];
    const float* thr     = (const float*)d_in[3];
    const int*   numIter = (const int*)d_in[4];
    float* out = (float*)d_out;

    const int Brows = in_sizes[0] / M_DIM;   // 4096
    const int nblk  = Brows / ROWS;          // 256 blocks = 1/CU
    ista_mfma8<<<nblk, NTHREADS, 0, stream>>>(y, S, W, thr, numIter, out);
}